// Round 3
// baseline (287.104 us; speedup 1.0000x reference)
//
#include <hip/hip_runtime.h>
#include <cmath>

typedef __bf16 bf16x8 __attribute__((ext_vector_type(8)));
typedef float  f32x4  __attribute__((ext_vector_type(4)));

// GEMM: BM=256 (=M), BN=64, BK=64, 512 threads (8 waves), depth-2 pipeline.
#define ATILE 32768        // one A tile: 256 rows * 128B (bf16, swizzled)
#define LDS_W_OFF 65536    // W buffers after the two A buffers
#define WTILE 8192         // one W tile: 64 rows * 128B (bf16, swizzled)
// LDS total: 2*32KB (A) + 2*8KB (W) = 80KB -> 2 blocks/CU

#define GLOAD_LDS16(g, l)                                                    \
    __builtin_amdgcn_global_load_lds(                                        \
        (const __attribute__((address_space(1))) unsigned int*)(g),          \
        (__attribute__((address_space(3))) unsigned int*)(l), 16, 0, 0)

__device__ __forceinline__ int swz(int row, int byteInRow) {
    return row * 128 + (byteInRow ^ ((row & 7) << 4));
}

__device__ __forceinline__ bf16x8 cvt8(f32x4 a, f32x4 b) {
    bf16x8 r;
    r[0] = (__bf16)a[0]; r[1] = (__bf16)a[1]; r[2] = (__bf16)a[2]; r[3] = (__bf16)a[3];
    r[4] = (__bf16)b[0]; r[5] = (__bf16)b[1]; r[6] = (__bf16)b[2]; r[7] = (__bf16)b[3];
    return r;
}

// Build A0 = concat(cat,x,hid) bf16, K-tiled (64-col tiles) + swizzled.
__global__ __launch_bounds__(256)
void prep_xc(const float* __restrict__ cat, const float* __restrict__ x,
             const float* __restrict__ hid, unsigned char* __restrict__ A0)
{
    int id  = blockIdx.x * 256 + threadIdx.x;   // 256*4096/8 ids
    int row = id >> 9, col = (id & 511) * 8;
    const float* src = (col < 512)  ? cat + (size_t)row * 512 + col
                     : (col < 2048) ? x   + (size_t)row * 1536 + (col - 512)
                                    : hid + (size_t)row * 2048 + (col - 2048);
    f32x4 a = *(const f32x4*)src, b = *(const f32x4*)(src + 4);
    int ks = col >> 6, c8 = (col & 63) >> 3;
    *(bf16x8*)(A0 + (size_t)ks * ATILE + swz(row, c8 * 16)) = cvt8(a, b);
}

// MODE 0: gates GEMM, split-K (2 halves -> 512 blocks), bias on half 0 only.
// MODE 1: vocab GEMM (W0 only), full K.
template <int MODE>
__global__ __launch_bounds__(512, 4)
void gemm_bf16(const unsigned char* __restrict__ At,
               const float* __restrict__ W0, const float* __restrict__ W1,
               const float* __restrict__ W2, const float* __restrict__ W3,
               const float* __restrict__ B0, const float* __restrict__ B1,
               const float* __restrict__ B2, const float* __restrict__ B3,
               float* __restrict__ out, int ldout)
{
    __shared__ __align__(16) unsigned char lds[2 * ATILE + 2 * WTILE];

    const int tid  = threadIdx.x;
    const int lane = tid & 63;
    const int wid  = tid >> 6;
    const int l15  = lane & 15;
    const int l4   = lane >> 4;
    const int wr   = wid >> 1;     // 0..3 -> 64 M-rows each
    const int wc   = wid & 1;      // 0..1 -> 32 N-cols each

    int n0, koff, nk; float* outp;
    if (MODE == 0) {
        n0 = (blockIdx.x >> 1) * 64;
        int kh = blockIdx.x & 1;
        koff = kh * 32; nk = 32;
        outp = out + (size_t)kh * 4194304;   // z0 / z1
    } else {
        n0 = blockIdx.x * 64; koff = 0; nk = 64; outp = out;
    }

    const float* Wsrc; const float* Bsrc; int wn0;
    if (MODE == 0) {
        int g = n0 >> 12;
        Wsrc = (g == 0) ? W0 : (g == 1) ? W1 : (g == 2) ? W2 : W3;
        Bsrc = (g == 0) ? B0 : (g == 1) ? B1 : (g == 2) ? B2 : B3;
        wn0  = n0 & 4095;
    } else {
        Wsrc = W0; Bsrc = B0; wn0 = n0;
    }

    f32x4 wreg[2][2];            // 2 pipeline slots of W staging regs
    f32x4 acc[4][2] = {};

    const int wrow = tid >> 3, wc8 = tid & 7;
    const float* wbase = Wsrc + (size_t)(wn0 + wrow) * 4096 + wc8 * 8;

    auto issueA = [&](int ks, int buf) {
        const unsigned char* src = At + (size_t)(koff + ks) * ATILE + wid * 4096 + lane * 16;
        unsigned char* dst = lds + buf * ATILE + wid * 4096;
        #pragma unroll
        for (int i = 0; i < 4; ++i)
            GLOAD_LDS16(src + i * 1024, dst + i * 1024);
    };
    auto loadW = [&](int ks, int slot) {
        const float* p = wbase + (size_t)(koff + ks) * 64;
        wreg[slot][0] = *(const f32x4*)p;
        wreg[slot][1] = *(const f32x4*)(p + 4);
    };
    auto storeW = [&](int slot, int buf) {
        *(bf16x8*)(lds + LDS_W_OFF + buf * WTILE + swz(wrow, wc8 * 16)) =
            cvt8(wreg[slot][0], wreg[slot][1]);
    };

    // prologue: tiles 0 and 1 in flight; W(0) staged to LDS
    issueA(0, 0); loadW(0, 0);
    issueA(1, 1); loadW(1, 1);
    asm volatile("s_waitcnt vmcnt(6)" ::: "memory");   // tile-0 ops done
    __builtin_amdgcn_sched_barrier(0);
    storeW(0, 0);
    asm volatile("s_waitcnt lgkmcnt(0)" ::: "memory");
    __builtin_amdgcn_s_barrier();

    for (int t = 0; t < nk; ++t) {
        const int cur = t & 1;
        unsigned char* abase = lds + cur * ATILE;
        unsigned char* wlds  = lds + LDS_W_OFF + cur * WTILE;

        // phase1: pull tile t fragments LDS -> VGPR, then free the buffer
        bf16x8 af[2][4], bw[2][2];
        #pragma unroll
        for (int kk = 0; kk < 2; ++kk) {
            #pragma unroll
            for (int m = 0; m < 4; ++m) {
                int row = wr * 64 + m * 16 + l15;
                af[kk][m] = *(const bf16x8*)(abase + swz(row, kk * 64 + l4 * 16));
            }
            #pragma unroll
            for (int n = 0; n < 2; ++n) {
                int row = wc * 32 + n * 16 + l15;
                bw[kk][n] = *(const bf16x8*)(wlds + swz(row, kk * 64 + l4 * 16));
            }
        }
        asm volatile("s_waitcnt lgkmcnt(0)" ::: "memory");
        __builtin_amdgcn_sched_barrier(0);
        __builtin_amdgcn_s_barrier();          // buffers cur are now reusable
        __builtin_amdgcn_sched_barrier(0);

        // phase2: issue tile t+2 into the freed buffers, MFMA on t,
        // then land tile t+1 (counted wait -- t+2 stays in flight)
        if (t + 2 < nk) { issueA(t + 2, cur); loadW(t + 2, cur); }
        #pragma unroll
        for (int kk = 0; kk < 2; ++kk)
            #pragma unroll
            for (int m = 0; m < 4; ++m)
                #pragma unroll
                for (int n = 0; n < 2; ++n)
                    acc[m][n] = __builtin_amdgcn_mfma_f32_16x16x32_bf16(
                        af[kk][m], bw[kk][n], acc[m][n], 0, 0, 0);
        if (t + 1 < nk) {
            if (t + 2 < nk) asm volatile("s_waitcnt vmcnt(6)" ::: "memory");
            else            asm volatile("s_waitcnt vmcnt(0)" ::: "memory");
            __builtin_amdgcn_sched_barrier(0);
            storeW(cur ^ 1, cur ^ 1);
            asm volatile("s_waitcnt lgkmcnt(0)" ::: "memory");
        }
        __builtin_amdgcn_s_barrier();
        __builtin_amdgcn_sched_barrier(0);
    }

    // epilogue: C/D map col=lane&15, row=(lane>>4)*4+j
    #pragma unroll
    for (int n = 0; n < 2; ++n) {
        int col = wc * 32 + n * 16 + l15;
        float bias = (MODE == 1 || koff == 0) ? Bsrc[wn0 + col] : 0.0f;
        #pragma unroll
        for (int m = 0; m < 4; ++m) {
            int row = wr * 64 + m * 16 + l4 * 4;
            f32x4 v = acc[m][n];
            #pragma unroll
            for (int j = 0; j < 4; ++j)
                outp[(size_t)(row + j) * ldout + n0 + col] = v[j] + bias;
        }
    }
}

// gates (z0+z1) -> cell_new/hidden_new + bf16-tiled hidden for gemm1
__global__ __launch_bounds__(256)
void lstm_elem(const float* __restrict__ z0, const float* __restrict__ z1,
               const float* __restrict__ cell,
               float* __restrict__ cnew, float* __restrict__ hnew,
               unsigned char* __restrict__ A1)
{
    int id  = blockIdx.x * 256 + threadIdx.x;
    int row = id >> 9, col = (id & 511) * 8;
    const float* za = z0 + (size_t)row * 16384 + col;
    const float* zb = z1 + (size_t)row * 16384 + col;
    f32x4 vf[2], vi[2], vg[2], vo[2];
    #pragma unroll
    for (int h = 0; h < 2; ++h) {
        vf[h] = *(const f32x4*)(za + h * 4)         + *(const f32x4*)(zb + h * 4);
        vi[h] = *(const f32x4*)(za + 4096 + h * 4)  + *(const f32x4*)(zb + 4096 + h * 4);
        vg[h] = *(const f32x4*)(za + 8192 + h * 4)  + *(const f32x4*)(zb + 8192 + h * 4);
        vo[h] = *(const f32x4*)(za + 12288 + h * 4) + *(const f32x4*)(zb + 12288 + h * 4);
    }
    const float* cr = cell + (size_t)row * 4096 + col;
    f32x4 vc[2] = { *(const f32x4*)cr, *(const f32x4*)(cr + 4) };
    f32x4 rc[2], rh[2];
    bf16x8 hb;
    #pragma unroll
    for (int h = 0; h < 2; ++h)
        #pragma unroll
        for (int j = 0; j < 4; ++j) {
            float f = 1.0f / (1.0f + __expf(-vf[h][j]));
            float i = 1.0f / (1.0f + __expf(-vi[h][j]));
            float g = tanhf(vg[h][j]);
            float o = 1.0f / (1.0f + __expf(-vo[h][j]));
            float cn = f * vc[h][j] + i * g;
            float hn = o * tanhf(cn);
            rc[h][j] = cn; rh[h][j] = hn;
            hb[h * 4 + j] = (__bf16)hn;
        }
    float* cd = cnew + (size_t)row * 4096 + col;
    float* hd = hnew + (size_t)row * 4096 + col;
    *(f32x4*)cd = rc[0]; *(f32x4*)(cd + 4) = rc[1];
    *(f32x4*)hd = rh[0]; *(f32x4*)(hd + 4) = rh[1];
    int ks = col >> 6, c8 = (col & 63) >> 3;
    *(bf16x8*)(A1 + (size_t)ks * ATILE + swz(row, c8 * 16)) = hb;
}

__global__ __launch_bounds__(256)
void logsoftmax_inplace(float* __restrict__ out)
{
    float* row    = out + (size_t)blockIdx.x * 32000;
    const int tid = threadIdx.x;
    __shared__ float redm[4], reds[4];

    float m = -1e30f, s = 0.0f;
    for (int i = tid; i < 8000; i += 256) {
        f32x4 v = *(const f32x4*)(row + i * 4);
        float t = fmaxf(fmaxf(v[0], v[1]), fmaxf(v[2], v[3]));
        float nm = fmaxf(m, t);
        s = s * __expf(m - nm) + __expf(v[0] - nm) + __expf(v[1] - nm)
                               + __expf(v[2] - nm) + __expf(v[3] - nm);
        m = nm;
    }
    #pragma unroll
    for (int off = 32; off; off >>= 1) {
        float om = __shfl_xor(m, off), os = __shfl_xor(s, off);
        float nm = fmaxf(m, om);
        s = s * __expf(m - nm) + os * __expf(om - nm);
        m = nm;
    }
    if ((tid & 63) == 0) { redm[tid >> 6] = m; reds[tid >> 6] = s; }
    __syncthreads();
    {
        float M = fmaxf(fmaxf(redm[0], redm[1]), fmaxf(redm[2], redm[3]));
        float S = reds[0] * __expf(redm[0] - M) + reds[1] * __expf(redm[1] - M)
                + reds[2] * __expf(redm[2] - M) + reds[3] * __expf(redm[3] - M);
        m = M; s = S;
    }
    float lse = m + logf(s);

    for (int i = tid; i < 8000; i += 256) {
        f32x4 v = *(const f32x4*)(row + i * 4);
        v[0] -= lse; v[1] -= lse; v[2] -= lse; v[3] -= lse;
        *(f32x4*)(row + i * 4) = v;
    }
}

extern "C" void kernel_launch(void* const* d_in, const int* in_sizes, int n_in,
                              void* d_out, int out_size, void* d_ws, size_t ws_size,
                              hipStream_t stream)
{
    const float* cat  = (const float*)d_in[0];
    const float* x    = (const float*)d_in[1];
    const float* hid  = (const float*)d_in[2];
    const float* cell = (const float*)d_in[3];
    const float* Wf   = (const float*)d_in[4];
    const float* bf   = (const float*)d_in[5];
    const float* Wi   = (const float*)d_in[6];
    const float* bi   = (const float*)d_in[7];
    const float* Wc   = (const float*)d_in[8];
    const float* bc   = (const float*)d_in[9];
    const float* Wo   = (const float*)d_in[10];
    const float* bo   = (const float*)d_in[11];
    const float* Wout = (const float*)d_in[12];
    const float* bout = (const float*)d_in[13];
    float* out = (float*)d_out;

    // ws: A0 (2MB) | A1 (2MB) | z0 (16MB) | z1 (16MB)
    unsigned char* A0 = (unsigned char*)d_ws;
    unsigned char* A1 = A0 + (size_t)64 * ATILE;
    float*         z  = (float*)(A1 + (size_t)64 * ATILE);  // z0; z1 = z+4194304

    // d_out: [logits 256x32000 | cell_new 256x4096 | hidden_new 256x4096]
    float* cnew = out + 8192000;
    float* hnew = out + 9240576;

    prep_xc<<<512, 256, 0, stream>>>(cat, x, hid, A0);
    // gates GEMM, split-K: 512 blocks (2/CU), halves write z0/z1
    gemm_bf16<0><<<512, 512, 0, stream>>>(A0, Wf, Wi, Wc, Wo, bf, bi, bc, bo, z, 16384);
    lstm_elem<<<512, 256, 0, stream>>>(z, z + 4194304, cell, cnew, hnew, A1);
    gemm_bf16<1><<<500, 512, 0, stream>>>(A1, Wout, Wout, Wout, Wout,
                                          bout, bout, bout, bout, out, 32000);
    logsoftmax_inplace<<<256, 256, 0, stream>>>(out);
}

// Round 4
// 276.213 us; speedup vs baseline: 1.0394x; 1.0394x over previous
//
#include <hip/hip_runtime.h>
#include <cmath>

typedef __bf16 bf16x8 __attribute__((ext_vector_type(8)));
typedef float  f32x4  __attribute__((ext_vector_type(4)));

template <int N> struct IC { static constexpr int v = N; };

// GEMM: BM=256 (=M), BN=128, BK=64, 512 threads (8 waves), depth-2 pipeline,
// compile-time double-buffer indices (rule #20: no runtime-indexed reg arrays).
#define ATILE 32768        // A tile: 256 rows * 128B (bf16, swizzled)
#define WTILE 16384        // W tile: 128 rows * 128B (bf16, swizzled)
#define LDS_W_OFF 65536    // after 2 A buffers
// LDS total: 2*32KB + 2*16KB = 96KB -> 1 block/CU

#define GLOAD_LDS16(g, l)                                                    \
    __builtin_amdgcn_global_load_lds(                                        \
        (const __attribute__((address_space(1))) unsigned int*)(g),          \
        (__attribute__((address_space(3))) unsigned int*)(l), 16, 0, 0)

__device__ __forceinline__ int swz(int row, int byteInRow) {
    return row * 128 + (byteInRow ^ ((row & 7) << 4));
}

__device__ __forceinline__ bf16x8 cvt8(f32x4 a, f32x4 b) {
    bf16x8 r;
    r[0] = (__bf16)a[0]; r[1] = (__bf16)a[1]; r[2] = (__bf16)a[2]; r[3] = (__bf16)a[3];
    r[4] = (__bf16)b[0]; r[5] = (__bf16)b[1]; r[6] = (__bf16)b[2]; r[7] = (__bf16)b[3];
    return r;
}

__global__ __launch_bounds__(256)
void prep_xc(const float* __restrict__ cat, const float* __restrict__ x,
             const float* __restrict__ hid, unsigned char* __restrict__ A0)
{
    int id  = blockIdx.x * 256 + threadIdx.x;
    int row = id >> 9, col = (id & 511) * 8;
    const float* src = (col < 512)  ? cat + (size_t)row * 512 + col
                     : (col < 2048) ? x   + (size_t)row * 1536 + (col - 512)
                                    : hid + (size_t)row * 2048 + (col - 2048);
    f32x4 a = *(const f32x4*)src, b = *(const f32x4*)(src + 4);
    int ks = col >> 6, c8 = (col & 63) >> 3;
    *(bf16x8*)(A0 + (size_t)ks * ATILE + swz(row, c8 * 16)) = cvt8(a, b);
}

// MODE 0: gates GEMM, split-K (2 halves -> 256 blocks), bias on half 0 only.
// MODE 1: vocab GEMM, full K (250 blocks).
template <int MODE>
__global__ __launch_bounds__(512, 2)
void gemm_bf16(const unsigned char* __restrict__ At,
               const float* __restrict__ W0, const float* __restrict__ W1,
               const float* __restrict__ W2, const float* __restrict__ W3,
               const float* __restrict__ B0, const float* __restrict__ B1,
               const float* __restrict__ B2, const float* __restrict__ B3,
               float* __restrict__ out, int ldout)
{
    __shared__ __align__(16) unsigned char lds[2 * ATILE + 2 * WTILE];

    constexpr int NKT = (MODE == 0) ? 32 : 64;

    const int tid  = threadIdx.x;
    const int lane = tid & 63;
    const int wid  = tid >> 6;
    const int l15  = lane & 15;
    const int l4   = lane >> 4;
    const int wr   = wid >> 1;     // 0..3 -> 64 M-rows each
    const int wc   = wid & 1;      // 0..1 -> 64 N-cols each

    int n0, koff; float* outp;
    if (MODE == 0) {
        n0 = (blockIdx.x >> 1) * 128;
        int kh = blockIdx.x & 1;
        koff = kh * 32;
        outp = out + (size_t)kh * 4194304;   // z0 / z1
    } else {
        n0 = blockIdx.x * 128; koff = 0; outp = out;
    }

    const float* Wsrc; const float* Bsrc; int wn0;
    if (MODE == 0) {
        int g = n0 >> 12;
        Wsrc = (g == 0) ? W0 : (g == 1) ? W1 : (g == 2) ? W2 : W3;
        Bsrc = (g == 0) ? B0 : (g == 1) ? B1 : (g == 2) ? B2 : B3;
        wn0  = n0 & 4095;
    } else {
        Wsrc = W0; Bsrc = B0; wn0 = n0;
    }

    f32x4 wreg[2][4];            // [pipeline slot][4x f32x4] -- slot always constexpr
    f32x4 acc[4][4] = {};

    const int wrow = tid >> 2;           // 0..127
    const int wkc  = tid & 3;            // 16-col chunk within 64
    const float* wbase = Wsrc + (size_t)(wn0 + wrow) * 4096 + (size_t)koff * 64 + wkc * 16;

    auto issueA = [&](int ks, int buf) {
        const unsigned char* src = At + (size_t)(koff + ks) * ATILE + wid * 4096 + lane * 16;
        unsigned char* dst = lds + buf * ATILE + wid * 4096;
        #pragma unroll
        for (int i = 0; i < 4; ++i)
            GLOAD_LDS16(src + i * 1024, dst + i * 1024);
    };
    auto loadW = [&](int ks, auto slot) {
        constexpr int S = decltype(slot)::v;
        const float* p = wbase + (size_t)ks * 64;
        wreg[S][0] = *(const f32x4*)p;
        wreg[S][1] = *(const f32x4*)(p + 4);
        wreg[S][2] = *(const f32x4*)(p + 8);
        wreg[S][3] = *(const f32x4*)(p + 12);
    };
    auto storeW = [&](auto slot, int buf) {
        constexpr int S = decltype(slot)::v;
        unsigned char* b = lds + LDS_W_OFF + buf * WTILE;
        *(bf16x8*)(b + swz(wrow, wkc * 32))      = cvt8(wreg[S][0], wreg[S][1]);
        *(bf16x8*)(b + swz(wrow, wkc * 32 + 16)) = cvt8(wreg[S][2], wreg[S][3]);
    };

    // prologue: tiles 0,1 in flight (8 vmem ops each); W(0) staged
    issueA(0, 0); loadW(0, IC<0>{});
    issueA(1, 1); loadW(1, IC<1>{});
    asm volatile("s_waitcnt vmcnt(8)" ::: "memory");
    __builtin_amdgcn_sched_barrier(0);
    storeW(IC<0>{}, 0);
    asm volatile("s_waitcnt lgkmcnt(0)" ::: "memory");
    __builtin_amdgcn_s_barrier();
    __builtin_amdgcn_sched_barrier(0);

    auto step = [&](int t, auto curc) {
        constexpr int CUR = decltype(curc)::v;
        constexpr int OTH = CUR ^ 1;
        unsigned char* abase = lds + CUR * ATILE;
        unsigned char* wlds  = lds + LDS_W_OFF + CUR * WTILE;

        // phase1: tile t LDS -> VGPR
        bf16x8 af[2][4], bw[2][4];
        #pragma unroll
        for (int kk = 0; kk < 2; ++kk) {
            #pragma unroll
            for (int m = 0; m < 4; ++m) {
                int row = wr * 64 + m * 16 + l15;
                af[kk][m] = *(const bf16x8*)(abase + swz(row, kk * 64 + l4 * 16));
            }
            #pragma unroll
            for (int n = 0; n < 4; ++n) {
                int row = wc * 64 + n * 16 + l15;
                bw[kk][n] = *(const bf16x8*)(wlds + swz(row, kk * 64 + l4 * 16));
            }
        }
        asm volatile("s_waitcnt lgkmcnt(0)" ::: "memory");
        __builtin_amdgcn_sched_barrier(0);
        __builtin_amdgcn_s_barrier();          // buffer CUR reusable
        __builtin_amdgcn_sched_barrier(0);

        // phase2: issue t+2 into freed buffer, MFMA on t, land t+1
        if (t + 2 < NKT) { issueA(t + 2, CUR); loadW(t + 2, curc); }
        #pragma unroll
        for (int kk = 0; kk < 2; ++kk)
            #pragma unroll
            for (int m = 0; m < 4; ++m)
                #pragma unroll
                for (int n = 0; n < 4; ++n)
                    acc[m][n] = __builtin_amdgcn_mfma_f32_16x16x32_bf16(
                        af[kk][m], bw[kk][n], acc[m][n], 0, 0, 0);
        if (t + 1 < NKT) {
            if (t + 2 < NKT) asm volatile("s_waitcnt vmcnt(8)" ::: "memory");
            else             asm volatile("s_waitcnt vmcnt(0)" ::: "memory");
            __builtin_amdgcn_sched_barrier(0);
            storeW(IC<OTH>{}, OTH);
            asm volatile("s_waitcnt lgkmcnt(0)" ::: "memory");
        }
        __builtin_amdgcn_s_barrier();
        __builtin_amdgcn_sched_barrier(0);
    };

    for (int t = 0; t < NKT; t += 2) {
        step(t,     IC<0>{});
        step(t + 1, IC<1>{});
    }

    // epilogue: C/D map col=lane&15, row=(lane>>4)*4+j
    #pragma unroll
    for (int n = 0; n < 4; ++n) {
        int col = wc * 64 + n * 16 + l15;
        float bias = (MODE == 1 || koff == 0) ? Bsrc[wn0 + col] : 0.0f;
        #pragma unroll
        for (int m = 0; m < 4; ++m) {
            int row = wr * 64 + m * 16 + l4 * 4;
            f32x4 v = acc[m][n];
            #pragma unroll
            for (int j = 0; j < 4; ++j)
                outp[(size_t)(row + j) * ldout + n0 + col] = v[j] + bias;
        }
    }
}

__global__ __launch_bounds__(256)
void lstm_elem(const float* __restrict__ z0, const float* __restrict__ z1,
               const float* __restrict__ cell,
               float* __restrict__ cnew, float* __restrict__ hnew,
               unsigned char* __restrict__ A1)
{
    int id  = blockIdx.x * 256 + threadIdx.x;
    int row = id >> 9, col = (id & 511) * 8;
    const float* za = z0 + (size_t)row * 16384 + col;
    const float* zb = z1 + (size_t)row * 16384 + col;
    f32x4 vf[2], vi[2], vg[2], vo[2];
    #pragma unroll
    for (int h = 0; h < 2; ++h) {
        vf[h] = *(const f32x4*)(za + h * 4)         + *(const f32x4*)(zb + h * 4);
        vi[h] = *(const f32x4*)(za + 4096 + h * 4)  + *(const f32x4*)(zb + 4096 + h * 4);
        vg[h] = *(const f32x4*)(za + 8192 + h * 4)  + *(const f32x4*)(zb + 8192 + h * 4);
        vo[h] = *(const f32x4*)(za + 12288 + h * 4) + *(const f32x4*)(zb + 12288 + h * 4);
    }
    const float* cr = cell + (size_t)row * 4096 + col;
    f32x4 vc[2] = { *(const f32x4*)cr, *(const f32x4*)(cr + 4) };
    f32x4 rc[2], rh[2];
    bf16x8 hb;
    #pragma unroll
    for (int h = 0; h < 2; ++h)
        #pragma unroll
        for (int j = 0; j < 4; ++j) {
            float f = 1.0f / (1.0f + __expf(-vf[h][j]));
            float i = 1.0f / (1.0f + __expf(-vi[h][j]));
            float g = tanhf(vg[h][j]);
            float o = 1.0f / (1.0f + __expf(-vo[h][j]));
            float cn = f * vc[h][j] + i * g;
            float hn = o * tanhf(cn);
            rc[h][j] = cn; rh[h][j] = hn;
            hb[h * 4 + j] = (__bf16)hn;
        }
    float* cd = cnew + (size_t)row * 4096 + col;
    float* hd = hnew + (size_t)row * 4096 + col;
    *(f32x4*)cd = rc[0]; *(f32x4*)(cd + 4) = rc[1];
    *(f32x4*)hd = rh[0]; *(f32x4*)(hd + 4) = rh[1];
    int ks = col >> 6, c8 = (col & 63) >> 3;
    *(bf16x8*)(A1 + (size_t)ks * ATILE + swz(row, c8 * 16)) = hb;
}

__global__ __launch_bounds__(256)
void logsoftmax_inplace(float* __restrict__ out)
{
    float* row    = out + (size_t)blockIdx.x * 32000;
    const int tid = threadIdx.x;
    __shared__ float redm[4], reds[4];

    float m = -1e30f, s = 0.0f;
    for (int i = tid; i < 8000; i += 256) {
        f32x4 v = *(const f32x4*)(row + i * 4);
        float t = fmaxf(fmaxf(v[0], v[1]), fmaxf(v[2], v[3]));
        float nm = fmaxf(m, t);
        s = s * __expf(m - nm) + __expf(v[0] - nm) + __expf(v[1] - nm)
                               + __expf(v[2] - nm) + __expf(v[3] - nm);
        m = nm;
    }
    #pragma unroll
    for (int off = 32; off; off >>= 1) {
        float om = __shfl_xor(m, off), os = __shfl_xor(s, off);
        float nm = fmaxf(m, om);
        s = s * __expf(m - nm) + os * __expf(om - nm);
        m = nm;
    }
    if ((tid & 63) == 0) { redm[tid >> 6] = m; reds[tid >> 6] = s; }
    __syncthreads();
    {
        float M = fmaxf(fmaxf(redm[0], redm[1]), fmaxf(redm[2], redm[3]));
        float S = reds[0] * __expf(redm[0] - M) + reds[1] * __expf(redm[1] - M)
                + reds[2] * __expf(redm[2] - M) + reds[3] * __expf(redm[3] - M);
        m = M; s = S;
    }
    float lse = m + logf(s);

    for (int i = tid; i < 8000; i += 256) {
        f32x4 v = *(const f32x4*)(row + i * 4);
        v[0] -= lse; v[1] -= lse; v[2] -= lse; v[3] -= lse;
        *(f32x4*)(row + i * 4) = v;
    }
}

extern "C" void kernel_launch(void* const* d_in, const int* in_sizes, int n_in,
                              void* d_out, int out_size, void* d_ws, size_t ws_size,
                              hipStream_t stream)
{
    const float* cat  = (const float*)d_in[0];
    const float* x    = (const float*)d_in[1];
    const float* hid  = (const float*)d_in[2];
    const float* cell = (const float*)d_in[3];
    const float* Wf   = (const float*)d_in[4];
    const float* bf   = (const float*)d_in[5];
    const float* Wi   = (const float*)d_in[6];
    const float* bi   = (const float*)d_in[7];
    const float* Wc   = (const float*)d_in[8];
    const float* bc   = (const float*)d_in[9];
    const float* Wo   = (const float*)d_in[10];
    const float* bo   = (const float*)d_in[11];
    const float* Wout = (const float*)d_in[12];
    const float* bout = (const float*)d_in[13];
    float* out = (float*)d_out;

    // ws: A0 (2MB) | A1 (2MB) | z0 (16MB) | z1 (16MB)
    unsigned char* A0 = (unsigned char*)d_ws;
    unsigned char* A1 = A0 + (size_t)64 * ATILE;
    float*         z  = (float*)(A1 + (size_t)64 * ATILE);

    // d_out: [logits 256x32000 | cell_new 256x4096 | hidden_new 256x4096]
    float* cnew = out + 8192000;
    float* hnew = out + 9240576;

    prep_xc<<<512, 256, 0, stream>>>(cat, x, hid, A0);
    gemm_bf16<0><<<256, 512, 0, stream>>>(A0, Wf, Wi, Wc, Wo, bf, bi, bc, bo, z, 16384);
    lstm_elem<<<512, 256, 0, stream>>>(z, z + 4194304, cell, cnew, hnew, A1);
    gemm_bf16<1><<<250, 512, 0, stream>>>(A1, Wout, Wout, Wout, Wout,
                                          bout, bout, bout, bout, out, 32000);
    logsoftmax_inplace<<<256, 256, 0, stream>>>(out);
}